// Round 12
// baseline (978.114 us; speedup 1.0000x reference)
//
#include <hip/hip_runtime.h>
#include <cstdint>
#include <cstddef>

#define EPG 160
#define HC  3072
#define DD  1024

typedef _Float16 f16x8 __attribute__((ext_vector_type(8)));
typedef _Float16 f16x4 __attribute__((ext_vector_type(4)));
typedef _Float16 f16x2 __attribute__((ext_vector_type(2)));
typedef float    f32x4 __attribute__((ext_vector_type(4)));

__device__ __forceinline__ unsigned fenc(float f){
  unsigned u = __float_as_uint(f);
  return (u & 0x80000000u) ? ~u : (u | 0x80000000u);
}
__device__ __forceinline__ float fdec(unsigned u){
  return (u & 0x80000000u) ? __uint_as_float(u ^ 0x80000000u) : __uint_as_float(~u);
}

__device__ __forceinline__ void gload16(const void* g, void* l) {
  __builtin_amdgcn_global_load_lds((const __attribute__((address_space(1))) void*)g,
                                   (__attribute__((address_space(3))) void*)l, 16, 0, 0);
}

// ---------------- weight transpose + fp16 split (pre-swizzled chunks) ----------------
__global__ __launch_bounds__(256) void wtrans_kernel(
    const float* __restrict__ W, _Float16* __restrict__ WTh, _Float16* __restrict__ WTl,
    int K, int Nn)
{
  __shared__ float t[32][33];
  const int tx = threadIdx.x, ty = threadIdx.y;
  const int n0 = blockIdx.x * 32, k0 = blockIdx.y * 32;
  #pragma unroll
  for (int i = 0; i < 4; i++) {
    int k = k0 + ty + i * 8;
    t[ty + i * 8][tx] = (k < K) ? W[(size_t)k * Nn + n0 + tx] : 0.f;
  }
  __syncthreads();
  const int kt = k0 >> 5;
  const int c  = tx >> 3;
  const int w8 = tx & 7;
  #pragma unroll
  for (int i = 0; i < 4; i++) {
    int n = n0 + ty + i * 8;
    float v = t[tx][ty + i * 8];
    _Float16 h = (_Float16)v;
    float r = v - (float)h;
    int c2 = c ^ ((n >> 1) & 3);
    size_t addr = ((size_t)kt * Nn + n) * 32 + c2 * 8 + w8;
    WTh[addr] = h;
    WTl[addr] = (_Float16)r;
  }
}

// ---------------- prep: ||p_i||, w_as/w_ad = g1W . a_{src,dst}, bp_i = t_ib . p_i ----------------
__global__ __launch_bounds__(256) void prep_kernel(
    const float* __restrict__ p1, const float* __restrict__ p2, const float* __restrict__ p3,
    const float* __restrict__ g1W, const float* __restrict__ g1as, const float* __restrict__ g1ad,
    const float* __restrict__ t1b, const float* __restrict__ t2b, const float* __restrict__ t3b,
    float* __restrict__ nrm, float* __restrict__ was, float* __restrict__ wad,
    float* __restrict__ bp)
{
  const int b = blockIdx.x;
  const int tid = threadIdx.x;
  __shared__ float red[4];
  if (b < 3) {
    const float* p = b == 0 ? p1 : (b == 1 ? p2 : p3);
    float s = 0.f;
    for (int i = tid; i < DD; i += 256) { float v = p[i]; s += v * v; }
    #pragma unroll
    for (int off = 32; off; off >>= 1) s += __shfl_down(s, off);
    if ((tid & 63) == 0) red[tid >> 6] = s;
    __syncthreads();
    if (tid == 0) nrm[b] = sqrtf(red[0] + red[1] + red[2] + red[3]);
  } else if (b < 9) {
    const int idx = b - 3;
    const int h = idx >> 1;
    const float* av = (idx & 1) ? g1ad : g1as;
    float* outv = (idx & 1) ? wad : was;
    for (int j = 0; j < 30; j++) {
      float s = 0.f;
      for (int c = tid; c < DD; c += 256)
        s += g1W[(size_t)j * HC + h * DD + c] * av[h * DD + c];
      #pragma unroll
      for (int off = 32; off; off >>= 1) s += __shfl_down(s, off);
      if ((tid & 63) == 0) red[tid >> 6] = s;
      __syncthreads();
      if (tid == 0) outv[h * 32 + j] = red[0] + red[1] + red[2] + red[3];
      __syncthreads();
    }
    if (tid == 0) { outv[h * 32 + 30] = 0.f; outv[h * 32 + 31] = 0.f; }
  } else {
    const int i = b - 9;
    const float* tb = i == 0 ? t1b : (i == 1 ? t2b : t3b);
    const float* p = i == 0 ? p1 : (i == 1 ? p2 : p3);
    float s = 0.f;
    for (int c = tid; c < DD; c += 256) s += tb[c] * p[c];
    #pragma unroll
    for (int off = 32; off; off >>= 1) s += __shfl_down(s, off);
    if ((tid & 63) == 0) red[tid >> 6] = s;
    __syncthreads();
    if (tid == 0) bp[i] = red[0] + red[1] + red[2] + red[3];
  }
}

// ---------------- vproj: V[i][j] = sum_d t_iW[j][d] * p_i[d] ----------------
__global__ __launch_bounds__(64) void vproj_kernel(
    const float* __restrict__ t1W, const float* __restrict__ t2W, const float* __restrict__ t3W,
    const float* __restrict__ p1, const float* __restrict__ p2, const float* __restrict__ p3,
    float* __restrict__ V)
{
  const int j = blockIdx.x;
  const int i = blockIdx.y;
  const float* Wm = i == 0 ? t1W : (i == 1 ? t2W : t3W);
  const float* p  = i == 0 ? p1 : (i == 1 ? p2 : p3);
  const int lane = threadIdx.x;
  const float* row = Wm + (size_t)j * DD;
  float s = 0.f;
  #pragma unroll 4
  for (int c = lane; c < DD; c += 64) s += row[c] * p[c];
  #pragma unroll
  for (int off = 32; off; off >>= 1) s += __shfl_down(s, off);
  if (lane == 0) V[i * HC + j] = s;
}

// ---------------- fused stage-1: g1 projection (K=30) + attention + aggregation + score ----
// LDS reads vectorized to ds_read_b128 (sP pitch 36 for 16B alignment).
__global__ __launch_bounds__(256) void gat_fused1(
    const float* __restrict__ x, const float* __restrict__ g1W,
    const float* __restrict__ was, const float* __restrict__ wad,
    const int* __restrict__ esrc, const int* __restrict__ edst,
    const float* __restrict__ gbias,
    _Float16* __restrict__ ATh, _Float16* __restrict__ ATl, int Mtot,
    const float* __restrict__ V, float* __restrict__ scp)
{
  const int g = blockIdx.x;
  const int h = blockIdx.y >> 1;
  const int half = blockIdx.y & 1;
  const int tid = threadIdx.x;
  const int base = g << 5;
  __shared__ __align__(16) float sx[32][32];
  __shared__ __align__(16) float sP[32][36];
  __shared__ float s_as[32], s_ad[32], s_mx[32], s_den[32];
  __shared__ unsigned s_mxu[32];

  for (int i = tid; i < 1024; i += 256) {
    int n = i >> 5, j = i & 31;
    sx[n][j] = (j < 30) ? x[(size_t)(base + n) * 30 + j] : 0.f;
  }
  for (int i = tid; i < 32 * 36; i += 256) ((float*)sP)[i] = 0.f;
  if (tid < 32) { s_mxu[tid] = 0u; s_den[tid] = 0.f; }
  __syncthreads();

  const int colb = h * DD + (half << 9);
  const int c = colb + (tid << 1);
  float w0[32], w1[32];
  #pragma unroll
  for (int j = 0; j < 30; j++) {
    float2 wv = *(const float2*)&g1W[(size_t)j * HC + c];
    w0[j] = wv.x; w1[j] = wv.y;
  }
  w0[30] = 0.f; w0[31] = 0.f; w1[30] = 0.f; w1[31] = 0.f;

  if (tid < 32) {
    float ps = 0.f, pd2 = 0.f;
    #pragma unroll
    for (int j = 0; j < 30; j++) {
      float xv = sx[tid][j];
      ps  += xv * was[h * 32 + j];
      pd2 += xv * wad[h * 32 + j];
    }
    s_as[tid] = ps; s_ad[tid] = pd2;
  }
  __syncthreads();

  int sl = 0, dl = 0;
  float lg = 0.f;
  if (tid < EPG) {
    int ei = g * EPG + tid;
    sl = esrc[ei] - base; dl = edst[ei] - base;
    float v = s_as[sl] + s_ad[dl];
    lg = v > 0.f ? v : 0.2f * v;
    atomicMax(&s_mxu[dl], fenc(lg));
  }
  float slg = 0.f;
  if (tid < 32) {
    float v = s_as[tid] + s_ad[tid];
    slg = v > 0.f ? v : 0.2f * v;
    atomicMax(&s_mxu[tid], fenc(slg));
  }
  __syncthreads();
  if (tid < 32) s_mx[tid] = fdec(s_mxu[tid]);
  __syncthreads();
  float ex = 0.f;
  if (tid < EPG) { ex = expf(lg - s_mx[dl]); atomicAdd(&s_den[dl], ex); }
  float exs = 0.f;
  if (tid < 32) { exs = expf(slg - s_mx[tid]); atomicAdd(&s_den[tid], exs); }
  __syncthreads();
  if (tid < EPG) atomicAdd(&sP[dl][sl], ex / s_den[dl]);
  if (tid < 32)  atomicAdd(&sP[tid][tid], exs / s_den[tid]);

  // xl columns for all 32 nodes (float4 LDS reads, fully unrolled -> static indexing)
  float xl0[32], xl1[32];
  #pragma unroll
  for (int n = 0; n < 32; n++) {
    float a0 = 0.f, a1 = 0.f;
    #pragma unroll
    for (int j4 = 0; j4 < 8; j4++) {
      const float4 xv = *(const float4*)&sx[n][j4 * 4];
      a0 += xv.x * w0[j4*4+0] + xv.y * w0[j4*4+1] + xv.z * w0[j4*4+2] + xv.w * w0[j4*4+3];
      a1 += xv.x * w1[j4*4+0] + xv.y * w1[j4*4+1] + xv.z * w1[j4*4+2] + xv.w * w1[j4*4+3];
    }
    xl0[n] = a0; xl1[n] = a1;
  }
  __syncthreads();   // sP final

  const float b0 = gbias[c], b1 = gbias[c + 1];
  const float v0c = V[c], v1c = V[c + 1];
  const int slot = blockIdx.y * 4 + (tid >> 6);
  const int kt = c >> 5;
  const int ch = (c >> 3) & 3;
  const int j2 = c & 7;
  for (int n = 0; n < 32; n++) {
    float a0 = 0.f, a1 = 0.f;
    #pragma unroll
    for (int m4 = 0; m4 < 8; m4++) {
      const float4 p4 = *(const float4*)&sP[n][m4 * 4];
      a0 += p4.x * xl0[m4*4+0] + p4.y * xl0[m4*4+1] + p4.z * xl0[m4*4+2] + p4.w * xl0[m4*4+3];
      a1 += p4.x * xl1[m4*4+0] + p4.y * xl1[m4*4+1] + p4.z * xl1[m4*4+2] + p4.w * xl1[m4*4+3];
    }
    a0 += b0; a1 += b1;
    float sc = a0 * v0c + a1 * v1c;
    #pragma unroll
    for (int off = 32; off; off >>= 1) sc += __shfl_xor(sc, off);
    if ((tid & 63) == 0) scp[(size_t)(base + n) * 24 + slot] = sc;
    const int R = base + n;
    const int c2 = ch ^ ((R >> 1) & 3);
    const size_t ad = ((size_t)kt * Mtot + R) * 32 + c2 * 8 + j2;
    f16x2 hh, ll;
    _Float16 h0 = (_Float16)a0; hh[0] = h0; ll[0] = (_Float16)(a0 - (float)h0);
    _Float16 h1 = (_Float16)a1; hh[1] = h1; ll[1] = (_Float16)(a1 - (float)h1);
    *(f16x2*)&ATh[ad] = hh;
    *(f16x2*)&ATl[ad] = ll;
  }
}

// ---------------- split-fp16 MFMA GEMM (g-mode: alsp; t-mode: rowmap gather + gated epilogue) ----
__global__ __launch_bounds__(256) void mfma_gemm(
    const _Float16* __restrict__ ATh, const _Float16* __restrict__ ATl,
    const _Float16* __restrict__ BTh, const _Float16* __restrict__ BTl,
    const float* __restrict__ bias, float* __restrict__ C,
    int M, int N, int K, int Msrc,
    const float* __restrict__ avs, const float* __restrict__ avd,
    float* __restrict__ alsp, float* __restrict__ aldp,
    const int* __restrict__ rowmap, const float* __restrict__ scores)
{
  __shared__ __align__(16) char smem[2 * 32768];

  const int gx = N >> 7, gy = M >> 7;
  const int lid = blockIdx.x + gx * blockIdx.y;
  int vx, vy;
  const int G = gy & ~7;
  if (lid < gx * G) {
    const int sub = lid & 7, rest = lid >> 3;
    vx = rest % gx; vy = (rest / gx) * 8 + sub;
  } else {
    const int r = lid - gx * G;
    vx = r % gx; vy = G + r / gx;
  }
  const int brow = vy << 7, bcol = vx << 7;

  const int tid  = threadIdx.x;
  const int lane = tid & 63;
  const int w    = tid >> 6;
  const int wr   = (w >> 1) << 6, wc = (w & 1) << 6;
  const int wn   = w & 1;
  const int fr   = lane & 15, g4 = lane >> 4;

  const int lr0 = tid >> 2;
  int r0g, r1g;
  if (rowmap) {
    r0g = rowmap[brow + lr0];
    r1g = rowmap[brow + 64 + lr0];
  } else {
    r0g = brow + lr0;
    r1g = brow + 64 + lr0;
  }
  const int ch0 = (((tid & 3) ^ ((lr0 >> 1) & 3) ^ ((r0g >> 1) & 3)) << 4);
  const int ch1 = (((tid & 3) ^ ((lr0 >> 1) & 3) ^ ((r1g >> 1) & 3)) << 4);

  f32x4 acc[4][4];
  #pragma unroll
  for (int m = 0; m < 4; m++)
    #pragma unroll
    for (int n = 0; n < 4; n++) acc[m][n] = (f32x4)0.0f;

  int aoff[4], boff[4];
  #pragma unroll
  for (int m = 0; m < 4; m++) {
    int r = wr + m * 16 + fr;
    aoff[m] = r * 64 + ((g4 ^ ((r >> 1) & 3)) << 4);
  }
  #pragma unroll
  for (int n = 0; n < 4; n++) {
    int r = wc + n * 16 + fr;
    boff[n] = r * 64 + ((g4 ^ ((r >> 1) & 3)) << 4);
  }

  const int ktiles = (K + 31) >> 5;

#define STAGE(ktv, buf)                                                        \
  do {                                                                         \
    char* bse = (buf);                                                         \
    const size_t a0ad = (((size_t)(ktv) * Msrc + r0g) << 6) + ch0;             \
    const size_t a1ad = (((size_t)(ktv) * Msrc + r1g) << 6) + ch1;             \
    const size_t bb = (((size_t)(ktv) * N + bcol) << 6) + tid * 16;            \
    gload16((const char*)ATh + a0ad, bse + tid * 16);                          \
    gload16((const char*)ATh + a1ad, bse + tid * 16 + 4096);                   \
    gload16((const char*)ATl + a0ad, bse + 8192 + tid * 16);                   \
    gload16((const char*)ATl + a1ad, bse + 8192 + tid * 16 + 4096);            \
    gload16((const char*)BTh + bb,        bse + 16384 + tid * 16);             \
    gload16((const char*)BTh + bb + 4096, bse + 16384 + tid * 16 + 4096);      \
    gload16((const char*)BTl + bb,        bse + 24576 + tid * 16);             \
    gload16((const char*)BTl + bb + 4096, bse + 24576 + tid * 16 + 4096);      \
  } while (0)

  STAGE(0, smem);
  if (ktiles > 1) STAGE(1, smem + 32768);

  for (int kt = 0; kt < ktiles; kt++) {
    char* curb = smem + ((kt & 1) << 15);
    if (kt + 1 < ktiles) {
      asm volatile("s_waitcnt vmcnt(8)" ::: "memory");
    } else {
      asm volatile("s_waitcnt vmcnt(0)" ::: "memory");
    }
    __builtin_amdgcn_s_barrier();
    asm volatile("" ::: "memory");

    f16x8 ah[4], al[4], bh[4], bl[4];
    #pragma unroll
    for (int n = 0; n < 4; n++) {
      bh[n] = *(const f16x8*)(curb + 16384 + boff[n]);
      bl[n] = *(const f16x8*)(curb + 24576 + boff[n]);
    }
    #pragma unroll
    for (int m = 0; m < 4; m++) {
      ah[m] = *(const f16x8*)(curb + aoff[m]);
      al[m] = *(const f16x8*)(curb + 8192 + aoff[m]);
    }
    asm volatile("s_waitcnt lgkmcnt(0)" ::: "memory");
    __builtin_amdgcn_sched_barrier(0);
    __builtin_amdgcn_s_barrier();
    asm volatile("" ::: "memory");

    if (kt + 2 < ktiles) STAGE(kt + 2, curb);

    __builtin_amdgcn_s_setprio(1);
    #pragma unroll
    for (int m = 0; m < 4; m++) {
      #pragma unroll
      for (int n = 0; n < 4; n++) {
        acc[m][n] = __builtin_amdgcn_mfma_f32_16x16x32_f16(ah[m], bh[n], acc[m][n], 0, 0, 0);
        acc[m][n] = __builtin_amdgcn_mfma_f32_16x16x32_f16(al[m], bh[n], acc[m][n], 0, 0, 0);
        acc[m][n] = __builtin_amdgcn_mfma_f32_16x16x32_f16(ah[m], bl[n], acc[m][n], 0, 0, 0);
      }
    }
    __builtin_amdgcn_s_setprio(0);
    asm volatile("" ::: "memory");
  }
#undef STAGE

  const int crow0 = brow + wr + g4 * 4;
  const int ccol0 = bcol + wc + fr;

  if (scores) {
    #pragma unroll
    for (int m = 0; m < 4; m++) {
      #pragma unroll
      for (int q = 0; q < 4; q++) {
        const int row = crow0 + m * 16 + q;
        const float s = scores[row];
        #pragma unroll
        for (int n = 0; n < 4; n++) {
          const int col = ccol0 + n * 16;
          C[(size_t)row * N + col] = (acc[m][n][q] + bias[col]) * s;
        }
      }
    }
  } else {
    #pragma unroll
    for (int n = 0; n < 4; n++) {
      const int col = ccol0 + n * 16;
      const float bv = bias ? bias[col] : 0.f;
      #pragma unroll
      for (int m = 0; m < 4; m++) {
        const int row = crow0 + m * 16;
        #pragma unroll
        for (int q = 0; q < 4; q++)
          C[(size_t)(row + q) * N + col] = acc[m][n][q] + bv;
      }
    }
  }

  if (alsp) {
    const int h3 = bcol >> 10;
    const int slot = ((bcol & 1023) >> 6) + wn;
    #pragma unroll
    for (int m = 0; m < 4; m++) {
      #pragma unroll
      for (int q = 0; q < 4; q++) {
        float ps = 0.f, pd = 0.f;
        #pragma unroll
        for (int n = 0; n < 4; n++) {
          const int col = ccol0 + n * 16;
          const float v = acc[m][n][q];
          ps += v * avs[col]; pd += v * avd[col];
        }
        #pragma unroll
        for (int mk = 1; mk <= 8; mk <<= 1) {
          ps += __shfl_xor(ps, mk);
          pd += __shfl_xor(pd, mk);
        }
        if (fr == 0) {
          const int row = crow0 + m * 16 + q;
          alsp[row * 48 + h3 * 16 + slot] = ps;
          aldp[row * 48 + h3 * 16 + slot] = pd;
        }
      }
    }
  }
}

// ---------------- fused GAT attention + aggregation (stages 2/3) + score partials ------------
__global__ __launch_bounds__(256) void gat_agg(
    const float* __restrict__ xl, const float* __restrict__ alsp, const float* __restrict__ aldp,
    const int* __restrict__ esrc, const int* __restrict__ edst, const int* __restrict__ emask,
    const float* __restrict__ gbias, _Float16* __restrict__ ATh, _Float16* __restrict__ ATl,
    int npg, int Mtot, const float* __restrict__ V, float* __restrict__ scp)
{
  const int g = blockIdx.x;
  const int h = blockIdx.y >> 1;
  const int half = blockIdx.y & 1;
  const int tid = threadIdx.x;
  const int base = g * npg;
  __shared__ float sxl[32 * 512];
  __shared__ float s_as[32], s_ad[32], s_mx[32], s_den[32], s_self[32];
  __shared__ unsigned s_mxu[32];
  __shared__ float s_alpha[EPG];
  __shared__ int s_srcl[EPG];
  __shared__ int s_start[33];
  __shared__ int s_cnt[32], s_cur[32];
  __shared__ int s_list[EPG];

  const int colb = h * DD + (half << 9);
  for (int n = 0; n < npg; n++) {
    *(float2*)&sxl[(n << 9) + (tid << 1)] =
        *(const float2*)&xl[(size_t)(base + n) * HC + colb + (tid << 1)];
  }

  if (tid < npg) {
    const float* ps = alsp + (size_t)(base + tid) * 48 + h * 16;
    const float* pdp = aldp + (size_t)(base + tid) * 48 + h * 16;
    float ss = 0.f, dd2 = 0.f;
    #pragma unroll
    for (int s = 0; s < 16; s++) { ss += ps[s]; dd2 += pdp[s]; }
    s_as[tid] = ss;
    s_ad[tid] = dd2;
    s_mxu[tid] = 0u;
    s_den[tid] = 0.f;
    s_cnt[tid] = 0;
    s_cur[tid] = 0;
  }
  __syncthreads();

  int ok = 0, dl = 0;
  float lg = 0.f;
  if (tid < EPG) {
    int ei = g * EPG + tid;
    ok = emask ? emask[ei] : 1;
    if (ok) {
      int sl = esrc[ei] - base;
      dl = edst[ei] - base;
      s_srcl[tid] = sl;
      float v = s_as[sl] + s_ad[dl];
      lg = v > 0.f ? v : 0.2f * v;
      atomicMax(&s_mxu[dl], fenc(lg));
      atomicAdd(&s_cnt[dl], 1);
    }
  }
  float slg = 0.f;
  if (tid < npg) {
    float v = s_as[tid] + s_ad[tid];
    slg = v > 0.f ? v : 0.2f * v;
    atomicMax(&s_mxu[tid], fenc(slg));
  }
  __syncthreads();

  if (tid < npg) s_mx[tid] = fdec(s_mxu[tid]);
  if (tid == 0) {
    int run = 0;
    for (int n = 0; n < npg; n++) { s_start[n] = run; run += s_cnt[n]; }
    s_start[npg] = run;
  }
  __syncthreads();

  float ex = 0.f;
  if (tid < EPG && ok) {
    ex = expf(lg - s_mx[dl]);
    atomicAdd(&s_den[dl], ex);
    int p = s_start[dl] + atomicAdd(&s_cur[dl], 1);
    s_list[p] = tid;
  }
  if (tid < npg) {
    float e2 = expf(slg - s_mx[tid]);
    s_self[tid] = e2;
    atomicAdd(&s_den[tid], e2);
  }
  __syncthreads();

  if (tid < EPG && ok) s_alpha[tid] = ex / s_den[dl];
  if (tid < npg) s_self[tid] = s_self[tid] / s_den[tid];
  __syncthreads();

  const int c = colb + (tid << 1);
  const float b0 = gbias[c], b1 = gbias[c + 1];
  const float v0c = V[c], v1c = V[c + 1];
  const int slot = blockIdx.y * 4 + (tid >> 6);
  const int kt = c >> 5;
  const int ch = (c >> 3) & 3;
  const int j2 = c & 7;
  for (int n = 0; n < npg; n++) {
    const float2 v = *(const float2*)&sxl[(n << 9) + (tid << 1)];
    float a0 = s_self[n];
    float ax = a0 * v.x, ay = a0 * v.y;
    const int st = s_start[n], en = s_start[n + 1];
    for (int q = st; q < en; q++) {
      int e = s_list[q];
      float a = s_alpha[e];
      const float2 u = *(const float2*)&sxl[(s_srcl[e] << 9) + (tid << 1)];
      ax += a * u.x; ay += a * u.y;
    }
    ax += b0; ay += b1;
    float sc = ax * v0c + ay * v1c;
    #pragma unroll
    for (int off = 32; off; off >>= 1) sc += __shfl_xor(sc, off);
    if ((tid & 63) == 0) scp[(size_t)(base + n) * 24 + slot] = sc;
    const int R = base + n;
    const int c2 = ch ^ ((R >> 1) & 3);
    const size_t ad = ((size_t)kt * Mtot + R) * 32 + c2 * 8 + j2;
    f16x2 hh, ll;
    _Float16 h0 = (_Float16)ax; hh[0] = h0; ll[0] = (_Float16)(ax - (float)h0);
    _Float16 h1 = (_Float16)ay; hh[1] = h1; ll[1] = (_Float16)(ay - (float)h1);
    *(f16x2*)&ATh[ad] = hh;
    *(f16x2*)&ATl[ad] = ll;
  }
}

// ---------------- select: scores -> stable top-k, rowmap + gating scores + edge remap --------
__global__ __launch_bounds__(256) void select_kernel(
    const float* __restrict__ scp, const float* __restrict__ nrm,
    const float* __restrict__ bp, int stage,
    const int* __restrict__ cs, const int* __restrict__ cd, const int* __restrict__ cm,
    int npg, int k,
    int* __restrict__ rowmap, float* __restrict__ scores,
    int* __restrict__ ns, int* __restrict__ nd, int* __restrict__ nm)
{
  int g = blockIdx.x, tid = threadIdx.x;
  __shared__ float ssc[32];
  __shared__ int sord[32];
  __shared__ int snp[32];
  if (tid < npg) {
    const float* sp = scp + (size_t)(g * npg + tid) * 24;
    float s = 0.f;
    #pragma unroll
    for (int q = 0; q < 24; q++) s += sp[q];
    ssc[tid] = tanhf((s + bp[stage]) / nrm[stage]);
  }
  __syncthreads();
  if (tid == 0) {
    for (int i = 0; i < npg; i++) sord[i] = i;
    for (int i = 1; i < npg; i++) {
      int oi = sord[i]; float v = ssc[oi]; int j = i - 1;
      while (j >= 0 && ssc[sord[j]] < v) { sord[j + 1] = sord[j]; j--; }
      sord[j + 1] = oi;
    }
  }
  __syncthreads();
  if (tid < npg) snp[tid] = -1;
  __syncthreads();
  if (tid < k) {
    snp[sord[tid]] = tid;
    rowmap[g * k + tid] = g * npg + sord[tid];
    scores[g * k + tid] = ssc[sord[tid]];
  }
  __syncthreads();

  for (int e = tid; e < EPG; e += 256) {
    int ei = g * EPG + e;
    int ok = cm ? cm[ei] : 1;
    int m2 = 0, a = 0, b2 = 0;
    if (ok) {
      int sl = cs[ei] - g * npg, dl = cd[ei] - g * npg;
      int nsl = snp[sl], ndl = snp[dl];
      if (nsl >= 0 && ndl >= 0) { m2 = 1; a = g * k + nsl; b2 = g * k + ndl; }
    }
    ns[ei] = a; nd[ei] = b2; nm[ei] = m2;
  }
}

// ---------------- gap: mean of k gated rows per graph + vectorized split-AX write ------------
__global__ __launch_bounds__(256) void gap_kernel(
    const float* __restrict__ xb, int k, float* __restrict__ gap,
    _Float16* __restrict__ ATh, _Float16* __restrict__ ATl, int Mnext)
{
  const int g = blockIdx.x, tid = threadIdx.x;
  const int col = tid << 2;
  const int kt = col >> 5;
  const int ch = (col >> 3) & 3;
  const int j4 = col & 7;                  // 0 or 4
  float a0 = 0.f, a1 = 0.f, a2 = 0.f, a3 = 0.f;
  for (int r = 0; r < k; r++) {
    const int R = g * k + r;
    const float4 v = *(const float4*)&xb[(((size_t)R) << 10) + col];
    a0 += v.x; a1 += v.y; a2 += v.z; a3 += v.w;
    if (ATh) {
      const int c2 = ch ^ ((R >> 1) & 3);
      const size_t ad = ((size_t)kt * Mnext + R) * 32 + c2 * 8 + j4;
      f16x4 hh, ll;
      _Float16 h0 = (_Float16)v.x; hh[0] = h0; ll[0] = (_Float16)(v.x - (float)h0);
      _Float16 h1 = (_Float16)v.y; hh[1] = h1; ll[1] = (_Float16)(v.y - (float)h1);
      _Float16 h2 = (_Float16)v.z; hh[2] = h2; ll[2] = (_Float16)(v.z - (float)h2);
      _Float16 h3 = (_Float16)v.w; hh[3] = h3; ll[3] = (_Float16)(v.w - (float)h3);
      *(f16x4*)&ATh[ad] = hh;
      *(f16x4*)&ATl[ad] = ll;
    }
  }
  const float fk = (float)k;
  float4 o = make_float4(a0 / fk, a1 / fk, a2 / fk, a3 / fk);
  *(float4*)&gap[((size_t)g << 10) + col] = o;
}

// ---------------- fused head ----------------
__global__ __launch_bounds__(256) void head_kernel(
    const float* __restrict__ X1, const float* __restrict__ X2, const float* __restrict__ X3,
    const float* __restrict__ l1W, const float* __restrict__ l1b,
    const float* __restrict__ l2W, float* __restrict__ partial)
{
  __shared__ float a[4][1024];
  __shared__ float red[4][4];
  const int tid = threadIdx.x;
  const int cg = blockIdx.x, rg = blockIdx.y;
  const int row0 = rg << 2;
  #pragma unroll
  for (int r = 0; r < 4; r++) {
    const size_t ro = (size_t)(row0 + r) << 10;
    #pragma unroll
    for (int jj = 0; jj < 4; jj++) {
      int j = tid + jj * 256;
      a[r][j] = X1[ro + j] + X2[ro + j] + X3[ro + j];
    }
  }
  __syncthreads();

  const int col = (cg << 8) + tid;
  float acc0 = 0.f, acc1 = 0.f, acc2 = 0.f, acc3 = 0.f;
  #pragma unroll 8
  for (int k = 0; k < 1024; k++) {
    float wv = l1W[((size_t)k << 10) + col];
    acc0 += a[0][k] * wv;
    acc1 += a[1][k] * wv;
    acc2 += a[2][k] * wv;
    acc3 += a[3][k] * wv;
  }
  const float bv = l1b[col], lw = l2W[col];
  float v0 = fmaxf(acc0 + bv, 0.f) * lw;
  float v1 = fmaxf(acc1 + bv, 0.f) * lw;
  float v2 = fmaxf(acc2 + bv, 0.f) * lw;
  float v3 = fmaxf(acc3 + bv, 0.f) * lw;
  #pragma unroll
  for (int off = 32; off; off >>= 1) {
    v0 += __shfl_down(v0, off);
    v1 += __shfl_down(v1, off);
    v2 += __shfl_down(v2, off);
    v3 += __shfl_down(v3, off);
  }
  const int lane = tid & 63, wid = tid >> 6;
  if (lane == 0) { red[wid][0] = v0; red[wid][1] = v1; red[wid][2] = v2; red[wid][3] = v3; }
  __syncthreads();
  if (tid < 4)
    partial[(size_t)(row0 + tid) * 4 + cg] =
        red[0][tid] + red[1][tid] + red[2][tid] + red[3][tid];
}

__global__ __launch_bounds__(256) void head2_kernel(
    const float* __restrict__ partial, const float* __restrict__ l2b,
    float* __restrict__ out)
{
  int r = threadIdx.x;
  out[r] = partial[r * 4 + 0] + partial[r * 4 + 1] +
           partial[r * 4 + 2] + partial[r * 4 + 3] + l2b[0];
}

extern "C" void kernel_launch(void* const* d_in, const int* in_sizes, int n_in,
                              void* d_out, int out_size, void* d_ws, size_t ws_size,
                              hipStream_t stream)
{
  (void)in_sizes; (void)n_in; (void)out_size; (void)ws_size;
  const float* x    = (const float*)d_in[0];
  const int*   eidx = (const int*)d_in[2];
  const float* g1W = (const float*)d_in[4];
  const float* g1as= (const float*)d_in[5];
  const float* g1ad= (const float*)d_in[6];
  const float* g1b = (const float*)d_in[7];
  const float* t1W = (const float*)d_in[8];
  const float* t1b = (const float*)d_in[9];
  const float* p1  = (const float*)d_in[10];
  const float* g2W = (const float*)d_in[11];
  const float* g2as= (const float*)d_in[12];
  const float* g2ad= (const float*)d_in[13];
  const float* g2b = (const float*)d_in[14];
  const float* t2W = (const float*)d_in[15];
  const float* t2b = (const float*)d_in[16];
  const float* p2  = (const float*)d_in[17];
  const float* g3W = (const float*)d_in[18];
  const float* g3as= (const float*)d_in[19];
  const float* g3ad= (const float*)d_in[20];
  const float* g3b = (const float*)d_in[21];
  const float* t3W = (const float*)d_in[22];
  const float* t3b = (const float*)d_in[23];
  const float* p3  = (const float*)d_in[24];
  const float* l1W = (const float*)d_in[25];
  const float* l1b = (const float*)d_in[26];
  const float* l2W = (const float*)d_in[27];
  const float* l2b = (const float*)d_in[28];
  float* outp = (float*)d_out;

  float* W = (float*)d_ws;
  size_t o = 0;
  float* bufA = W + o;                                   // g-GEMM fp32 C (<=6656*3072)
  float* bufB = bufA;                                    // ALIAS: t output (<=6656*1024)
  o += (size_t)6656 * HC;
  _Float16* ATAh = (_Float16*)(W + o); o += (size_t)96 * 8192 * 32 / 2; // agg split h (K=3072)
  _Float16* ATAl = (_Float16*)(W + o); o += (size_t)96 * 8192 * 32 / 2; // agg split l
  _Float16* AXh  = (_Float16*)(W + o); o += (size_t)32 * 6656 * 32 / 2; // x_new split h (K=1024)
  _Float16* AXl  = (_Float16*)(W + o); o += (size_t)32 * 6656 * 32 / 2; // x_new split l
  float* ALSp = W + o; o += 8192 * 48;
  float* ALDp = W + o; o += 8192 * 48;
  float* SCP  = W + o; o += 8192 * 24;
  float* NRM = W + o; o += 4;
  float* BP  = W + o; o += 4;
  float* WAS = W + o; o += 96;
  float* WAD = W + o; o += 96;
  float* V   = W + o; o += 3 * HC;
  float* X1  = W + o; o += 256 * DD;
  float* X2  = W + o; o += 256 * DD;
  float* X3  = W + o; o += 256 * DD;
  float* HP  = W + o; o += 256 * 4;
  float* SSEL = W + o; o += 6656;
  int* RMAP = (int*)(W + o); o += 6656;
  int* E0s = (int*)(W + o); o += 40960;
  int* E0d = (int*)(W + o); o += 40960;
  int* E0m = (int*)(W + o); o += 40960;
  int* E1s = (int*)(W + o); o += 40960;
  int* E1d = (int*)(W + o); o += 40960;
  int* E1m = (int*)(W + o); o += 40960;
  _Float16* WTH = (_Float16*)(W + o); o += (3200 * 1024) / 2;
  _Float16* WTL = (_Float16*)(W + o); o += (3200 * 1024) / 2;

  const int* es1 = eidx;
  const int* ed1 = eidx + 40960;

  prep_kernel<<<12, 256, 0, stream>>>(p1, p2, p3, g1W, g1as, g1ad, t1b, t2b, t3b,
                                      NRM, WAS, WAD, BP);
  vproj_kernel<<<dim3(HC, 3), 64, 0, stream>>>(t1W, t2W, t3W, p1, p2, p3, V);

  // -------- stage 1: 8192 rows, npg=32 -> k=26 (select-before-project) --------
  gat_fused1<<<dim3(256, 6), 256, 0, stream>>>(x, g1W, WAS, WAD, es1, ed1, g1b,
                                               ATAh, ATAl, 8192, V, SCP);
  select_kernel<<<256, 256, 0, stream>>>(SCP, NRM, BP, 0, es1, ed1, nullptr, 32, 26,
                                         RMAP, SSEL, E0s, E0d, E0m);
  wtrans_kernel<<<dim3(32, 96), dim3(32, 8), 0, stream>>>(t1W, WTH, WTL, HC, DD);
  mfma_gemm<<<dim3(8, 52), 256, 0, stream>>>(ATAh, ATAl, WTH, WTL, t1b, bufB,
                                             6656, DD, HC, 8192,
                                             nullptr, nullptr, nullptr, nullptr,
                                             RMAP, SSEL);
  gap_kernel<<<256, 256, 0, stream>>>(bufB, 26, X1, AXh, AXl, 6656);

  // -------- stage 2: M=6656, npg=26 -> k=13 --------
  wtrans_kernel<<<dim3(96, 32), dim3(32, 8), 0, stream>>>(g2W, WTH, WTL, DD, HC);
  mfma_gemm<<<dim3(24, 52), 256, 0, stream>>>(AXh, AXl, WTH, WTL, nullptr, bufA,
                                              6656, HC, DD, 6656,
                                              g2as, g2ad, ALSp, ALDp,
                                              nullptr, nullptr);
  gat_agg<<<dim3(256, 6), 256, 0, stream>>>(bufA, ALSp, ALDp, E0s, E0d, E0m, g2b,
                                            ATAh, ATAl, 26, 6656, V + HC, SCP);
  select_kernel<<<256, 256, 0, stream>>>(SCP, NRM, BP, 1, E0s, E0d, E0m, 26, 13,
                                         RMAP, SSEL, E1s, E1d, E1m);
  wtrans_kernel<<<dim3(32, 96), dim3(32, 8), 0, stream>>>(t2W, WTH, WTL, HC, DD);
  mfma_gemm<<<dim3(8, 26), 256, 0, stream>>>(ATAh, ATAl, WTH, WTL, t2b, bufB,
                                             3328, DD, HC, 6656,
                                             nullptr, nullptr, nullptr, nullptr,
                                             RMAP, SSEL);
  gap_kernel<<<256, 256, 0, stream>>>(bufB, 13, X2, AXh, AXl, 3328);

  // -------- stage 3: M=3328, npg=13 -> k=4 --------
  wtrans_kernel<<<dim3(96, 32), dim3(32, 8), 0, stream>>>(g3W, WTH, WTL, DD, HC);
  mfma_gemm<<<dim3(24, 26), 256, 0, stream>>>(AXh, AXl, WTH, WTL, nullptr, bufA,
                                              3328, HC, DD, 3328,
                                              g3as, g3ad, ALSp, ALDp,
                                              nullptr, nullptr);
  gat_agg<<<dim3(256, 6), 256, 0, stream>>>(bufA, ALSp, ALDp, E1s, E1d, E1m, g3b,
                                            ATAh, ATAl, 13, 3328, V + 2 * HC, SCP);
  select_kernel<<<256, 256, 0, stream>>>(SCP, NRM, BP, 2, E1s, E1d, E1m, 13, 4,
                                         RMAP, SSEL, E0s, E0d, E0m);
  wtrans_kernel<<<dim3(32, 96), dim3(32, 8), 0, stream>>>(t3W, WTH, WTL, HC, DD);
  mfma_gemm<<<dim3(8, 8), 256, 0, stream>>>(ATAh, ATAl, WTH, WTL, t3b, bufB,
                                            1024, DD, HC, 3328,
                                            nullptr, nullptr, nullptr, nullptr,
                                            RMAP, SSEL);
  gap_kernel<<<256, 256, 0, stream>>>(bufB, 4, X3, nullptr, nullptr, 0);

  // -------- fused head --------
  head_kernel<<<dim3(4, 64), 256, 0, stream>>>(X1, X2, X3, l1W, l1b, l2W, HP);
  head2_kernel<<<1, 256, 0, stream>>>(HP, l2b, outp);
}

// Round 13
// 959.342 us; speedup vs baseline: 1.0196x; 1.0196x over previous
//
#include <hip/hip_runtime.h>
#include <cstdint>
#include <cstddef>

#define EPG 160
#define HC  3072
#define DD  1024

typedef _Float16 f16x8 __attribute__((ext_vector_type(8)));
typedef _Float16 f16x2 __attribute__((ext_vector_type(2)));
typedef float    f32x4 __attribute__((ext_vector_type(4)));

__device__ __forceinline__ unsigned fenc(float f){
  unsigned u = __float_as_uint(f);
  return (u & 0x80000000u) ? ~u : (u | 0x80000000u);
}
__device__ __forceinline__ float fdec(unsigned u){
  return (u & 0x80000000u) ? __uint_as_float(u ^ 0x80000000u) : __uint_as_float(~u);
}

__device__ __forceinline__ void gload16(const void* g, void* l) {
  __builtin_amdgcn_global_load_lds((const __attribute__((address_space(1))) void*)g,
                                   (__attribute__((address_space(3))) void*)l, 16, 0, 0);
}

// ---------------- weight transpose + fp16 split (pre-swizzled chunks) ----------------
__global__ __launch_bounds__(256) void wtrans_kernel(
    const float* __restrict__ W, _Float16* __restrict__ WTh, _Float16* __restrict__ WTl,
    int K, int Nn)
{
  __shared__ float t[32][33];
  const int tx = threadIdx.x, ty = threadIdx.y;
  const int n0 = blockIdx.x * 32, k0 = blockIdx.y * 32;
  #pragma unroll
  for (int i = 0; i < 4; i++) {
    int k = k0 + ty + i * 8;
    t[ty + i * 8][tx] = (k < K) ? W[(size_t)k * Nn + n0 + tx] : 0.f;
  }
  __syncthreads();
  const int kt = k0 >> 5;
  const int c  = tx >> 3;
  const int w8 = tx & 7;
  #pragma unroll
  for (int i = 0; i < 4; i++) {
    int n = n0 + ty + i * 8;
    float v = t[tx][ty + i * 8];
    _Float16 h = (_Float16)v;
    float r = v - (float)h;
    int c2 = c ^ ((n >> 1) & 3);
    size_t addr = ((size_t)kt * Nn + n) * 32 + c2 * 8 + w8;
    WTh[addr] = h;
    WTl[addr] = (_Float16)r;
  }
}

// ---------------- prep: ||p_i||, w_as/w_ad = g1W . a_{src,dst}, bp_i = t_ib . p_i ----------------
__global__ __launch_bounds__(256) void prep_kernel(
    const float* __restrict__ p1, const float* __restrict__ p2, const float* __restrict__ p3,
    const float* __restrict__ g1W, const float* __restrict__ g1as, const float* __restrict__ g1ad,
    const float* __restrict__ t1b, const float* __restrict__ t2b, const float* __restrict__ t3b,
    float* __restrict__ nrm, float* __restrict__ was, float* __restrict__ wad,
    float* __restrict__ bp)
{
  const int b = blockIdx.x;
  const int tid = threadIdx.x;
  __shared__ float red[4];
  if (b < 3) {
    const float* p = b == 0 ? p1 : (b == 1 ? p2 : p3);
    float s = 0.f;
    for (int i = tid; i < DD; i += 256) { float v = p[i]; s += v * v; }
    #pragma unroll
    for (int off = 32; off; off >>= 1) s += __shfl_down(s, off);
    if ((tid & 63) == 0) red[tid >> 6] = s;
    __syncthreads();
    if (tid == 0) nrm[b] = sqrtf(red[0] + red[1] + red[2] + red[3]);
  } else if (b < 9) {
    const int idx = b - 3;
    const int h = idx >> 1;
    const float* av = (idx & 1) ? g1ad : g1as;
    float* outv = (idx & 1) ? wad : was;
    for (int j = 0; j < 30; j++) {
      float s = 0.f;
      for (int c = tid; c < DD; c += 256)
        s += g1W[(size_t)j * HC + h * DD + c] * av[h * DD + c];
      #pragma unroll
      for (int off = 32; off; off >>= 1) s += __shfl_down(s, off);
      if ((tid & 63) == 0) red[tid >> 6] = s;
      __syncthreads();
      if (tid == 0) outv[h * 32 + j] = red[0] + red[1] + red[2] + red[3];
      __syncthreads();
    }
    if (tid == 0) { outv[h * 32 + 30] = 0.f; outv[h * 32 + 31] = 0.f; }
  } else {
    const int i = b - 9;
    const float* tb = i == 0 ? t1b : (i == 1 ? t2b : t3b);
    const float* p = i == 0 ? p1 : (i == 1 ? p2 : p3);
    float s = 0.f;
    for (int c = tid; c < DD; c += 256) s += tb[c] * p[c];
    #pragma unroll
    for (int off = 32; off; off >>= 1) s += __shfl_down(s, off);
    if ((tid & 63) == 0) red[tid >> 6] = s;
    __syncthreads();
    if (tid == 0) bp[i] = red[0] + red[1] + red[2] + red[3];
  }
}

// ---------------- vproj: V[i][j] = sum_d t_iW[j][d] * p_i[d] ----------------
__global__ __launch_bounds__(64) void vproj_kernel(
    const float* __restrict__ t1W, const float* __restrict__ t2W, const float* __restrict__ t3W,
    const float* __restrict__ p1, const float* __restrict__ p2, const float* __restrict__ p3,
    float* __restrict__ V)
{
  const int j = blockIdx.x;
  const int i = blockIdx.y;
  const float* Wm = i == 0 ? t1W : (i == 1 ? t2W : t3W);
  const float* p  = i == 0 ? p1 : (i == 1 ? p2 : p3);
  const int lane = threadIdx.x;
  const float* row = Wm + (size_t)j * DD;
  float s = 0.f;
  #pragma unroll 4
  for (int c = lane; c < DD; c += 64) s += row[c] * p[c];
  #pragma unroll
  for (int off = 32; off; off >>= 1) s += __shfl_down(s, off);
  if (lane == 0) V[i * HC + j] = s;
}

// ---------------- fused stage-1: g1 projection (K=30) + attention + aggregation + score ----
__global__ __launch_bounds__(256) void gat_fused1(
    const float* __restrict__ x, const float* __restrict__ g1W,
    const float* __restrict__ was, const float* __restrict__ wad,
    const int* __restrict__ esrc, const int* __restrict__ edst,
    const float* __restrict__ gbias,
    _Float16* __restrict__ ATh, _Float16* __restrict__ ATl, int Mtot,
    const float* __restrict__ V, float* __restrict__ scp)
{
  const int g = blockIdx.x;
  const int h = blockIdx.y >> 1;
  const int half = blockIdx.y & 1;
  const int tid = threadIdx.x;
  const int base = g << 5;
  __shared__ float sx[32][32];
  __shared__ float sP[32][33];
  __shared__ float s_as[32], s_ad[32], s_mx[32], s_den[32];
  __shared__ unsigned s_mxu[32];

  for (int i = tid; i < 1024; i += 256) {
    int n = i >> 5, j = i & 31;
    sx[n][j] = (j < 30) ? x[(size_t)(base + n) * 30 + j] : 0.f;
  }
  for (int i = tid; i < 32 * 33; i += 256) ((float*)sP)[i] = 0.f;
  if (tid < 32) { s_mxu[tid] = 0u; s_den[tid] = 0.f; }
  __syncthreads();

  const int colb = h * DD + (half << 9);
  const int c = colb + (tid << 1);
  float w0[30], w1[30];
  #pragma unroll
  for (int j = 0; j < 30; j++) {
    float2 wv = *(const float2*)&g1W[(size_t)j * HC + c];
    w0[j] = wv.x; w1[j] = wv.y;
  }

  if (tid < 32) {
    float ps = 0.f, pd2 = 0.f;
    #pragma unroll
    for (int j = 0; j < 30; j++) {
      float xv = sx[tid][j];
      ps  += xv * was[h * 32 + j];
      pd2 += xv * wad[h * 32 + j];
    }
    s_as[tid] = ps; s_ad[tid] = pd2;
  }
  __syncthreads();

  int sl = 0, dl = 0;
  float lg = 0.f;
  if (tid < EPG) {
    int ei = g * EPG + tid;
    sl = esrc[ei] - base; dl = edst[ei] - base;
    float v = s_as[sl] + s_ad[dl];
    lg = v > 0.f ? v : 0.2f * v;
    atomicMax(&s_mxu[dl], fenc(lg));
  }
  float slg = 0.f;
  if (tid < 32) {
    float v = s_as[tid] + s_ad[tid];
    slg = v > 0.f ? v : 0.2f * v;
    atomicMax(&s_mxu[tid], fenc(slg));
  }
  __syncthreads();
  if (tid < 32) s_mx[tid] = fdec(s_mxu[tid]);
  __syncthreads();
  float ex = 0.f;
  if (tid < EPG) { ex = expf(lg - s_mx[dl]); atomicAdd(&s_den[dl], ex); }
  float exs = 0.f;
  if (tid < 32) { exs = expf(slg - s_mx[tid]); atomicAdd(&s_den[tid], exs); }
  __syncthreads();
  if (tid < EPG) atomicAdd(&sP[dl][sl], ex / s_den[dl]);
  if (tid < 32)  atomicAdd(&sP[tid][tid], exs / s_den[tid]);

  float xl0[32], xl1[32];
  #pragma unroll
  for (int n = 0; n < 32; n++) {
    float a0 = 0.f, a1 = 0.f;
    #pragma unroll
    for (int j = 0; j < 30; j++) {
      float xv = sx[n][j];
      a0 += xv * w0[j]; a1 += xv * w1[j];
    }
    xl0[n] = a0; xl1[n] = a1;
  }
  __syncthreads();   // sP final

  const float b0 = gbias[c], b1 = gbias[c + 1];
  const float v0c = V[c], v1c = V[c + 1];
  const int slot = blockIdx.y * 4 + (tid >> 6);
  const int kt = c >> 5;
  const int ch = (c >> 3) & 3;
  const int j2 = c & 7;
  for (int n = 0; n < 32; n++) {
    float a0 = 0.f, a1 = 0.f;
    #pragma unroll
    for (int m = 0; m < 32; m++) {
      float p = sP[n][m];
      a0 += p * xl0[m]; a1 += p * xl1[m];
    }
    a0 += b0; a1 += b1;
    float sc = a0 * v0c + a1 * v1c;
    #pragma unroll
    for (int off = 32; off; off >>= 1) sc += __shfl_xor(sc, off);
    if ((tid & 63) == 0) scp[(size_t)(base + n) * 24 + slot] = sc;
    const int R = base + n;
    const int c2 = ch ^ ((R >> 1) & 3);
    const size_t ad = ((size_t)kt * Mtot + R) * 32 + c2 * 8 + j2;
    f16x2 hh, ll;
    _Float16 h0 = (_Float16)a0; hh[0] = h0; ll[0] = (_Float16)(a0 - (float)h0);
    _Float16 h1 = (_Float16)a1; hh[1] = h1; ll[1] = (_Float16)(a1 - (float)h1);
    *(f16x2*)&ATh[ad] = hh;
    *(f16x2*)&ATl[ad] = ll;
  }
}

// ---------------- split-fp16 MFMA GEMM (g-mode: alsp; t-mode: rowmap gather + gated epilogue) ----
__global__ __launch_bounds__(256) void mfma_gemm(
    const _Float16* __restrict__ ATh, const _Float16* __restrict__ ATl,
    const _Float16* __restrict__ BTh, const _Float16* __restrict__ BTl,
    const float* __restrict__ bias, float* __restrict__ C,
    int M, int N, int K, int Msrc,
    const float* __restrict__ avs, const float* __restrict__ avd,
    float* __restrict__ alsp, float* __restrict__ aldp,
    const int* __restrict__ rowmap, const float* __restrict__ scores,
    _Float16* __restrict__ AXh, _Float16* __restrict__ AXl)
{
  __shared__ __align__(16) char smem[2 * 32768];

  const int gx = N >> 7, gy = M >> 7;
  const int lid = blockIdx.x + gx * blockIdx.y;
  int vx, vy;
  const int G = gy & ~7;
  if (lid < gx * G) {
    const int sub = lid & 7, rest = lid >> 3;
    vx = rest % gx; vy = (rest / gx) * 8 + sub;
  } else {
    const int r = lid - gx * G;
    vx = r % gx; vy = G + r / gx;
  }
  const int brow = vy << 7, bcol = vx << 7;

  const int tid  = threadIdx.x;
  const int lane = tid & 63;
  const int w    = tid >> 6;
  const int wr   = (w >> 1) << 6, wc = (w & 1) << 6;
  const int wn   = w & 1;
  const int fr   = lane & 15, g4 = lane >> 4;

  const int lr0 = tid >> 2;
  int r0g, r1g;
  if (rowmap) {
    r0g = rowmap[brow + lr0];
    r1g = rowmap[brow + 64 + lr0];
  } else {
    r0g = brow + lr0;
    r1g = brow + 64 + lr0;
  }
  const int ch0 = (((tid & 3) ^ ((lr0 >> 1) & 3) ^ ((r0g >> 1) & 3)) << 4);
  const int ch1 = (((tid & 3) ^ ((lr0 >> 1) & 3) ^ ((r1g >> 1) & 3)) << 4);

  f32x4 acc[4][4];
  #pragma unroll
  for (int m = 0; m < 4; m++)
    #pragma unroll
    for (int n = 0; n < 4; n++) acc[m][n] = (f32x4)0.0f;

  int aoff[4], boff[4];
  #pragma unroll
  for (int m = 0; m < 4; m++) {
    int r = wr + m * 16 + fr;
    aoff[m] = r * 64 + ((g4 ^ ((r >> 1) & 3)) << 4);
  }
  #pragma unroll
  for (int n = 0; n < 4; n++) {
    int r = wc + n * 16 + fr;
    boff[n] = r * 64 + ((g4 ^ ((r >> 1) & 3)) << 4);
  }

  const int ktiles = (K + 31) >> 5;

#define STAGE(ktv, buf)                                                        \
  do {                                                                         \
    char* bse = (buf);                                                         \
    const size_t a0ad = (((size_t)(ktv) * Msrc + r0g) << 6) + ch0;             \
    const size_t a1ad = (((size_t)(ktv) * Msrc + r1g) << 6) + ch1;             \
    const size_t bb = (((size_t)(ktv) * N + bcol) << 6) + tid * 16;            \
    gload16((const char*)ATh + a0ad, bse + tid * 16);                          \
    gload16((const char*)ATh + a1ad, bse + tid * 16 + 4096);                   \
    gload16((const char*)ATl + a0ad, bse + 8192 + tid * 16);                   \
    gload16((const char*)ATl + a1ad, bse + 8192 + tid * 16 + 4096);            \
    gload16((const char*)BTh + bb,        bse + 16384 + tid * 16);             \
    gload16((const char*)BTh + bb + 4096, bse + 16384 + tid * 16 + 4096);      \
    gload16((const char*)BTl + bb,        bse + 24576 + tid * 16);             \
    gload16((const char*)BTl + bb + 4096, bse + 24576 + tid * 16 + 4096);      \
  } while (0)

  STAGE(0, smem);
  if (ktiles > 1) STAGE(1, smem + 32768);

  for (int kt = 0; kt < ktiles; kt++) {
    char* curb = smem + ((kt & 1) << 15);
    if (kt + 1 < ktiles) {
      asm volatile("s_waitcnt vmcnt(8)" ::: "memory");
    } else {
      asm volatile("s_waitcnt vmcnt(0)" ::: "memory");
    }
    __builtin_amdgcn_s_barrier();
    asm volatile("" ::: "memory");

    f16x8 ah[4], al[4], bh[4], bl[4];
    #pragma unroll
    for (int n = 0; n < 4; n++) {
      bh[n] = *(const f16x8*)(curb + 16384 + boff[n]);
      bl[n] = *(const f16x8*)(curb + 24576 + boff[n]);
    }
    #pragma unroll
    for (int m = 0; m < 4; m++) {
      ah[m] = *(const f16x8*)(curb + aoff[m]);
      al[m] = *(const f16x8*)(curb + 8192 + aoff[m]);
    }
    asm volatile("s_waitcnt lgkmcnt(0)" ::: "memory");
    __builtin_amdgcn_sched_barrier(0);
    __builtin_amdgcn_s_barrier();
    asm volatile("" ::: "memory");

    if (kt + 2 < ktiles) STAGE(kt + 2, curb);

    __builtin_amdgcn_s_setprio(1);
    #pragma unroll
    for (int m = 0; m < 4; m++) {
      #pragma unroll
      for (int n = 0; n < 4; n++) {
        acc[m][n] = __builtin_amdgcn_mfma_f32_16x16x32_f16(ah[m], bh[n], acc[m][n], 0, 0, 0);
        acc[m][n] = __builtin_amdgcn_mfma_f32_16x16x32_f16(al[m], bh[n], acc[m][n], 0, 0, 0);
        acc[m][n] = __builtin_amdgcn_mfma_f32_16x16x32_f16(ah[m], bl[n], acc[m][n], 0, 0, 0);
      }
    }
    __builtin_amdgcn_s_setprio(0);
    asm volatile("" ::: "memory");
  }
#undef STAGE

  const int crow0 = brow + wr + g4 * 4;
  const int ccol0 = bcol + wc + fr;

  if (scores) {
    #pragma unroll
    for (int m = 0; m < 4; m++) {
      #pragma unroll
      for (int q = 0; q < 4; q++) {
        const int row = crow0 + m * 16 + q;
        const float s = scores[row];
        #pragma unroll
        for (int n = 0; n < 4; n++) {
          const int col = ccol0 + n * 16;
          const float gv = (acc[m][n][q] + bias[col]) * s;
          C[(size_t)row * N + col] = gv;
          if (AXh) {
            const int c2 = ((col >> 3) & 3) ^ ((row >> 1) & 3);
            const size_t ad = ((size_t)(col >> 5) * M + row) * 32 + c2 * 8 + (col & 7);
            _Float16 hv = (_Float16)gv;
            AXh[ad] = hv;
            AXl[ad] = (_Float16)(gv - (float)hv);
          }
        }
      }
    }
  } else {
    #pragma unroll
    for (int n = 0; n < 4; n++) {
      const int col = ccol0 + n * 16;
      const float bv = bias ? bias[col] : 0.f;
      #pragma unroll
      for (int m = 0; m < 4; m++) {
        const int row = crow0 + m * 16;
        #pragma unroll
        for (int q = 0; q < 4; q++)
          C[(size_t)(row + q) * N + col] = acc[m][n][q] + bv;
      }
    }
  }

  if (alsp) {
    const int h3 = bcol >> 10;
    const int slot = ((bcol & 1023) >> 6) + wn;
    #pragma unroll
    for (int m = 0; m < 4; m++) {
      #pragma unroll
      for (int q = 0; q < 4; q++) {
        float ps = 0.f, pd = 0.f;
        #pragma unroll
        for (int n = 0; n < 4; n++) {
          const int col = ccol0 + n * 16;
          const float v = acc[m][n][q];
          ps += v * avs[col]; pd += v * avd[col];
        }
        #pragma unroll
        for (int mk = 1; mk <= 8; mk <<= 1) {
          ps += __shfl_xor(ps, mk);
          pd += __shfl_xor(pd, mk);
        }
        if (fr == 0) {
          const int row = crow0 + m * 16 + q;
          alsp[row * 48 + h3 * 16 + slot] = ps;
          aldp[row * 48 + h3 * 16 + slot] = pd;
        }
      }
    }
  }
}

// ---------------- fused GAT attention + aggregation (stages 2/3) + score partials ------------
__global__ __launch_bounds__(256) void gat_agg(
    const float* __restrict__ xl, const float* __restrict__ alsp, const float* __restrict__ aldp,
    const int* __restrict__ esrc, const int* __restrict__ edst, const int* __restrict__ emask,
    const float* __restrict__ gbias, _Float16* __restrict__ ATh, _Float16* __restrict__ ATl,
    int npg, int Mtot, const float* __restrict__ V, float* __restrict__ scp)
{
  const int g = blockIdx.x;
  const int h = blockIdx.y >> 1;
  const int half = blockIdx.y & 1;
  const int tid = threadIdx.x;
  const int base = g * npg;
  __shared__ float sxl[32 * 512];
  __shared__ float s_as[32], s_ad[32], s_mx[32], s_den[32], s_self[32];
  __shared__ unsigned s_mxu[32];
  __shared__ float s_alpha[EPG];
  __shared__ int s_srcl[EPG];
  __shared__ int s_start[33];
  __shared__ int s_cnt[32], s_cur[32];
  __shared__ int s_list[EPG];

  const int colb = h * DD + (half << 9);
  for (int n = 0; n < npg; n++) {
    *(float2*)&sxl[(n << 9) + (tid << 1)] =
        *(const float2*)&xl[(size_t)(base + n) * HC + colb + (tid << 1)];
  }

  if (tid < npg) {
    const float* ps = alsp + (size_t)(base + tid) * 48 + h * 16;
    const float* pdp = aldp + (size_t)(base + tid) * 48 + h * 16;
    float ss = 0.f, dd2 = 0.f;
    #pragma unroll
    for (int s = 0; s < 16; s++) { ss += ps[s]; dd2 += pdp[s]; }
    s_as[tid] = ss;
    s_ad[tid] = dd2;
    s_mxu[tid] = 0u;
    s_den[tid] = 0.f;
    s_cnt[tid] = 0;
    s_cur[tid] = 0;
  }
  __syncthreads();

  int ok = 0, dl = 0;
  float lg = 0.f;
  if (tid < EPG) {
    int ei = g * EPG + tid;
    ok = emask ? emask[ei] : 1;
    if (ok) {
      int sl = esrc[ei] - base;
      dl = edst[ei] - base;
      s_srcl[tid] = sl;
      float v = s_as[sl] + s_ad[dl];
      lg = v > 0.f ? v : 0.2f * v;
      atomicMax(&s_mxu[dl], fenc(lg));
      atomicAdd(&s_cnt[dl], 1);
    }
  }
  float slg = 0.f;
  if (tid < npg) {
    float v = s_as[tid] + s_ad[tid];
    slg = v > 0.f ? v : 0.2f * v;
    atomicMax(&s_mxu[tid], fenc(slg));
  }
  __syncthreads();

  if (tid < npg) s_mx[tid] = fdec(s_mxu[tid]);
  if (tid == 0) {
    int run = 0;
    for (int n = 0; n < npg; n++) { s_start[n] = run; run += s_cnt[n]; }
    s_start[npg] = run;
  }
  __syncthreads();

  float ex = 0.f;
  if (tid < EPG && ok) {
    ex = expf(lg - s_mx[dl]);
    atomicAdd(&s_den[dl], ex);
    int p = s_start[dl] + atomicAdd(&s_cur[dl], 1);
    s_list[p] = tid;
  }
  if (tid < npg) {
    float e2 = expf(slg - s_mx[tid]);
    s_self[tid] = e2;
    atomicAdd(&s_den[tid], e2);
  }
  __syncthreads();

  if (tid < EPG && ok) s_alpha[tid] = ex / s_den[dl];
  if (tid < npg) s_self[tid] = s_self[tid] / s_den[tid];
  __syncthreads();

  const int c = colb + (tid << 1);
  const float b0 = gbias[c], b1 = gbias[c + 1];
  const float v0c = V[c], v1c = V[c + 1];
  const int slot = blockIdx.y * 4 + (tid >> 6);
  const int kt = c >> 5;
  const int ch = (c >> 3) & 3;
  const int j2 = c & 7;
  for (int n = 0; n < npg; n++) {
    const float2 v = *(const float2*)&sxl[(n << 9) + (tid << 1)];
    float a0 = s_self[n];
    float ax = a0 * v.x, ay = a0 * v.y;
    const int st = s_start[n], en = s_start[n + 1];
    for (int q = st; q < en; q++) {
      int e = s_list[q];
      float a = s_alpha[e];
      const float2 u = *(const float2*)&sxl[(s_srcl[e] << 9) + (tid << 1)];
      ax += a * u.x; ay += a * u.y;
    }
    ax += b0; ay += b1;
    float sc = ax * v0c + ay * v1c;
    #pragma unroll
    for (int off = 32; off; off >>= 1) sc += __shfl_xor(sc, off);
    if ((tid & 63) == 0) scp[(size_t)(base + n) * 24 + slot] = sc;
    const int R = base + n;
    const int c2 = ch ^ ((R >> 1) & 3);
    const size_t ad = ((size_t)kt * Mtot + R) * 32 + c2 * 8 + j2;
    f16x2 hh, ll;
    _Float16 h0 = (_Float16)ax; hh[0] = h0; ll[0] = (_Float16)(ax - (float)h0);
    _Float16 h1 = (_Float16)ay; hh[1] = h1; ll[1] = (_Float16)(ay - (float)h1);
    *(f16x2*)&ATh[ad] = hh;
    *(f16x2*)&ATl[ad] = ll;
  }
}

// ---------------- select: scores -> stable top-k, rowmap + gating scores + edge remap --------
__global__ __launch_bounds__(256) void select_kernel(
    const float* __restrict__ scp, const float* __restrict__ nrm,
    const float* __restrict__ bp, int stage,
    const int* __restrict__ cs, const int* __restrict__ cd, const int* __restrict__ cm,
    int npg, int k,
    int* __restrict__ rowmap, float* __restrict__ scores,
    int* __restrict__ ns, int* __restrict__ nd, int* __restrict__ nm)
{
  int g = blockIdx.x, tid = threadIdx.x;
  __shared__ float ssc[32];
  __shared__ int sord[32];
  __shared__ int snp[32];
  if (tid < npg) {
    const float* sp = scp + (size_t)(g * npg + tid) * 24;
    float s = 0.f;
    #pragma unroll
    for (int q = 0; q < 24; q++) s += sp[q];
    ssc[tid] = tanhf((s + bp[stage]) / nrm[stage]);
  }
  __syncthreads();
  if (tid == 0) {
    for (int i = 0; i < npg; i++) sord[i] = i;
    for (int i = 1; i < npg; i++) {
      int oi = sord[i]; float v = ssc[oi]; int j = i - 1;
      while (j >= 0 && ssc[sord[j]] < v) { sord[j + 1] = sord[j]; j--; }
      sord[j + 1] = oi;
    }
  }
  __syncthreads();
  if (tid < npg) snp[tid] = -1;
  __syncthreads();
  if (tid < k) {
    snp[sord[tid]] = tid;
    rowmap[g * k + tid] = g * npg + sord[tid];
    scores[g * k + tid] = ssc[sord[tid]];
  }
  __syncthreads();

  for (int e = tid; e < EPG; e += 256) {
    int ei = g * EPG + e;
    int ok = cm ? cm[ei] : 1;
    int m2 = 0, a = 0, b2 = 0;
    if (ok) {
      int sl = cs[ei] - g * npg, dl = cd[ei] - g * npg;
      int nsl = snp[sl], ndl = snp[dl];
      if (nsl >= 0 && ndl >= 0) { m2 = 1; a = g * k + nsl; b2 = g * k + ndl; }
    }
    ns[ei] = a; nd[ei] = b2; nm[ei] = m2;
  }
}

// ---------------- gap: mean of k gated rows per graph ----------------
__global__ __launch_bounds__(256) void gap_kernel(
    const float* __restrict__ xb, int k, float* __restrict__ gap)
{
  const int g = blockIdx.x, tid = threadIdx.x;
  float a0 = 0.f, a1 = 0.f, a2 = 0.f, a3 = 0.f;
  for (int r = 0; r < k; r++) {
    const float4 v = *(const float4*)&xb[(((size_t)(g * k + r)) << 10) + (tid << 2)];
    a0 += v.x; a1 += v.y; a2 += v.z; a3 += v.w;
  }
  const float fk = (float)k;
  float4 o = make_float4(a0 / fk, a1 / fk, a2 / fk, a3 / fk);
  *(float4*)&gap[((size_t)g << 10) + (tid << 2)] = o;
}

// ---------------- fused head ----------------
__global__ __launch_bounds__(256) void head_kernel(
    const float* __restrict__ X1, const float* __restrict__ X2, const float* __restrict__ X3,
    const float* __restrict__ l1W, const float* __restrict__ l1b,
    const float* __restrict__ l2W, float* __restrict__ partial)
{
  __shared__ float a[4][1024];
  __shared__ float red[4][4];
  const int tid = threadIdx.x;
  const int cg = blockIdx.x, rg = blockIdx.y;
  const int row0 = rg << 2;
  #pragma unroll
  for (int r = 0; r < 4; r++) {
    const size_t ro = (size_t)(row0 + r) << 10;
    #pragma unroll
    for (int jj = 0; jj < 4; jj++) {
      int j = tid + jj * 256;
      a[r][j] = X1[ro + j] + X2[ro + j] + X3[ro + j];
    }
  }
  __syncthreads();

  const int col = (cg << 8) + tid;
  float acc0 = 0.f, acc1 = 0.f, acc2 = 0.f, acc3 = 0.f;
  #pragma unroll 8
  for (int k = 0; k < 1024; k++) {
    float wv = l1W[((size_t)k << 10) + col];
    acc0 += a[0][k] * wv;
    acc1 += a[1][k] * wv;
    acc2 += a[2][k] * wv;
    acc3 += a[3][k] * wv;
  }
  const float bv = l1b[col], lw = l2W[col];
  float v0 = fmaxf(acc0 + bv, 0.f) * lw;
  float v1 = fmaxf(acc1 + bv, 0.f) * lw;
  float v2 = fmaxf(acc2 + bv, 0.f) * lw;
  float v3 = fmaxf(acc3 + bv, 0.f) * lw;
  #pragma unroll
  for (int off = 32; off; off >>= 1) {
    v0 += __shfl_down(v0, off);
    v1 += __shfl_down(v1, off);
    v2 += __shfl_down(v2, off);
    v3 += __shfl_down(v3, off);
  }
  const int lane = tid & 63, wid = tid >> 6;
  if (lane == 0) { red[wid][0] = v0; red[wid][1] = v1; red[wid][2] = v2; red[wid][3] = v3; }
  __syncthreads();
  if (tid < 4)
    partial[(size_t)(row0 + tid) * 4 + cg] =
        red[0][tid] + red[1][tid] + red[2][tid] + red[3][tid];
}

__global__ __launch_bounds__(256) void head2_kernel(
    const float* __restrict__ partial, const float* __restrict__ l2b,
    float* __restrict__ out)
{
  int r = threadIdx.x;
  out[r] = partial[r * 4 + 0] + partial[r * 4 + 1] +
           partial[r * 4 + 2] + partial[r * 4 + 3] + l2b[0];
}

extern "C" void kernel_launch(void* const* d_in, const int* in_sizes, int n_in,
                              void* d_out, int out_size, void* d_ws, size_t ws_size,
                              hipStream_t stream)
{
  (void)in_sizes; (void)n_in; (void)out_size; (void)ws_size;
  const float* x    = (const float*)d_in[0];
  const int*   eidx = (const int*)d_in[2];
  const float* g1W = (const float*)d_in[4];
  const float* g1as= (const float*)d_in[5];
  const float* g1ad= (const float*)d_in[6];
  const float* g1b = (const float*)d_in[7];
  const float* t1W = (const float*)d_in[8];
  const float* t1b = (const float*)d_in[9];
  const float* p1  = (const float*)d_in[10];
  const float* g2W = (const float*)d_in[11];
  const float* g2as= (const float*)d_in[12];
  const float* g2ad= (const float*)d_in[13];
  const float* g2b = (const float*)d_in[14];
  const float* t2W = (const float*)d_in[15];
  const float* t2b = (const float*)d_in[16];
  const float* p2  = (const float*)d_in[17];
  const float* g3W = (const float*)d_in[18];
  const float* g3as= (const float*)d_in[19];
  const float* g3ad= (const float*)d_in[20];
  const float* g3b = (const float*)d_in[21];
  const float* t3W = (const float*)d_in[22];
  const float* t3b = (const float*)d_in[23];
  const float* p3  = (const float*)d_in[24];
  const float* l1W = (const float*)d_in[25];
  const float* l1b = (const float*)d_in[26];
  const float* l2W = (const float*)d_in[27];
  const float* l2b = (const float*)d_in[28];
  float* outp = (float*)d_out;

  float* W = (float*)d_ws;
  size_t o = 0;
  float* bufA = W + o;                                   // g-GEMM fp32 C (<=6656*3072)
  float* bufB = bufA;                                    // ALIAS: t output (<=6656*1024)
  o += (size_t)6656 * HC;
  _Float16* ATAh = (_Float16*)(W + o); o += (size_t)96 * 8192 * 32 / 2; // agg split h (K=3072)
  _Float16* ATAl = (_Float16*)(W + o); o += (size_t)96 * 8192 * 32 / 2; // agg split l
  _Float16* AXh  = (_Float16*)(W + o); o += (size_t)32 * 6656 * 32 / 2; // x_new split h (K=1024)
  _Float16* AXl  = (_Float16*)(W + o); o += (size_t)32 * 6656 * 32 / 2; // x_new split l
  float* ALSp = W + o; o += 8192 * 48;
  float* ALDp = W + o; o += 8192 * 48;
  float* SCP  = W + o; o += 8192 * 24;
  float* NRM = W + o; o += 4;
  float* BP  = W + o; o += 4;
  float* WAS = W + o; o += 96;
  float* WAD = W + o; o += 96;
  float* V   = W + o; o += 3 * HC;
  float* X1  = W + o; o += 256 * DD;
  float* X2  = W + o; o += 256 * DD;
  float* X3  = W + o; o += 256 * DD;
  float* HP  = W + o; o += 256 * 4;
  float* SSEL = W + o; o += 6656;
  int* RMAP = (int*)(W + o); o += 6656;
  int* E0s = (int*)(W + o); o += 40960;
  int* E0d = (int*)(W + o); o += 40960;
  int* E0m = (int*)(W + o); o += 40960;
  int* E1s = (int*)(W + o); o += 40960;
  int* E1d = (int*)(W + o); o += 40960;
  int* E1m = (int*)(W + o); o += 40960;
  _Float16* WTH = (_Float16*)(W + o); o += (3200 * 1024) / 2;
  _Float16* WTL = (_Float16*)(W + o); o += (3200 * 1024) / 2;

  const int* es1 = eidx;
  const int* ed1 = eidx + 40960;

  prep_kernel<<<12, 256, 0, stream>>>(p1, p2, p3, g1W, g1as, g1ad, t1b, t2b, t3b,
                                      NRM, WAS, WAD, BP);
  vproj_kernel<<<dim3(HC, 3), 64, 0, stream>>>(t1W, t2W, t3W, p1, p2, p3, V);

  // -------- stage 1: 8192 rows, npg=32 -> k=26 (select-before-project) --------
  gat_fused1<<<dim3(256, 6), 256, 0, stream>>>(x, g1W, WAS, WAD, es1, ed1, g1b,
                                               ATAh, ATAl, 8192, V, SCP);
  select_kernel<<<256, 256, 0, stream>>>(SCP, NRM, BP, 0, es1, ed1, nullptr, 32, 26,
                                         RMAP, SSEL, E0s, E0d, E0m);
  wtrans_kernel<<<dim3(32, 96), dim3(32, 8), 0, stream>>>(t1W, WTH, WTL, HC, DD);
  mfma_gemm<<<dim3(8, 52), 256, 0, stream>>>(ATAh, ATAl, WTH, WTL, t1b, bufB,
                                             6656, DD, HC, 8192,
                                             nullptr, nullptr, nullptr, nullptr,
                                             RMAP, SSEL, AXh, AXl);
  gap_kernel<<<256, 256, 0, stream>>>(bufB, 26, X1);

  // -------- stage 2: M=6656, npg=26 -> k=13 --------
  wtrans_kernel<<<dim3(96, 32), dim3(32, 8), 0, stream>>>(g2W, WTH, WTL, DD, HC);
  mfma_gemm<<<dim3(24, 52), 256, 0, stream>>>(AXh, AXl, WTH, WTL, nullptr, bufA,
                                              6656, HC, DD, 6656,
                                              g2as, g2ad, ALSp, ALDp,
                                              nullptr, nullptr, nullptr, nullptr);
  gat_agg<<<dim3(256, 6), 256, 0, stream>>>(bufA, ALSp, ALDp, E0s, E0d, E0m, g2b,
                                            ATAh, ATAl, 26, 6656, V + HC, SCP);
  select_kernel<<<256, 256, 0, stream>>>(SCP, NRM, BP, 1, E0s, E0d, E0m, 26, 13,
                                         RMAP, SSEL, E1s, E1d, E1m);
  wtrans_kernel<<<dim3(32, 96), dim3(32, 8), 0, stream>>>(t2W, WTH, WTL, HC, DD);
  mfma_gemm<<<dim3(8, 26), 256, 0, stream>>>(ATAh, ATAl, WTH, WTL, t2b, bufB,
                                             3328, DD, HC, 6656,
                                             nullptr, nullptr, nullptr, nullptr,
                                             RMAP, SSEL, AXh, AXl);
  gap_kernel<<<256, 256, 0, stream>>>(bufB, 13, X2);

  // -------- stage 3: M=3328, npg=13 -> k=4 --------
  wtrans_kernel<<<dim3(96, 32), dim3(32, 8), 0, stream>>>(g3W, WTH, WTL, DD, HC);
  mfma_gemm<<<dim3(24, 26), 256, 0, stream>>>(AXh, AXl, WTH, WTL, nullptr, bufA,
                                              3328, HC, DD, 3328,
                                              g3as, g3ad, ALSp, ALDp,
                                              nullptr, nullptr, nullptr, nullptr);
  gat_agg<<<dim3(256, 6), 256, 0, stream>>>(bufA, ALSp, ALDp, E1s, E1d, E1m, g3b,
                                            ATAh, ATAl, 13, 3328, V + 2 * HC, SCP);
  select_kernel<<<256, 256, 0, stream>>>(SCP, NRM, BP, 2, E1s, E1d, E1m, 13, 4,
                                         RMAP, SSEL, E0s, E0d, E0m);
  wtrans_kernel<<<dim3(32, 96), dim3(32, 8), 0, stream>>>(t3W, WTH, WTL, HC, DD);
  mfma_gemm<<<dim3(8, 8), 256, 0, stream>>>(ATAh, ATAl, WTH, WTL, t3b, bufB,
                                            1024, DD, HC, 3328,
                                            nullptr, nullptr, nullptr, nullptr,
                                            RMAP, SSEL, nullptr, nullptr);
  gap_kernel<<<256, 256, 0, stream>>>(bufB, 4, X3);

  // -------- fused head --------
  head_kernel<<<dim3(4, 64), 256, 0, stream>>>(X1, X2, X3, l1W, l1b, l2W, HP);
  head2_kernel<<<1, 256, 0, stream>>>(HP, l2b, outp);
}